// Round 3
// baseline (97.941 us; speedup 1.0000x reference)
//
#include <hip/hip_runtime.h>
#include <cstdint>

// CharEmb: per word (B*S=16384): gather 32 char embeddings (E=64) -> x[64][32]
// (raw view of [32 chars][64] buffer), conv1d(F=128,K=3,valid,T=30), bias,
// max over t. Output float32 [16384][128].
//
// MFMA 32x32x16 bf16, M=t, N=f (layouts VERIFIED round 1, absmax 0.031):
//   D[t][f] = sum_kk sum_e xT[t+kk][e] * W[f][e][kk]
// Round 3: WAVE-PRIVATE words. Each wave computes ALL 128 f for its own words:
//  - 48 B-frags (weights) persistent in 192 VGPRs, 4 acc sets (64 AGPRs).
//  - A-frags read ONCE per word (12 ds_read_b128, was 48 across 4 waves).
//  - NO __syncthreads at all: LDS buffers are wave-private, write->read
//    ordering is same-wave (compiler lgkmcnt). ~330 unified regs -> 1 wave/SIMD.
//  - Per-word pipeline: gather(w+1)->regs | MFMA(w) | cvt+ds_write(w+1) | epi(w).

typedef __bf16 bf16x8 __attribute__((ext_vector_type(8)));
typedef float  f32x16 __attribute__((ext_vector_type(16)));

#define NW   16          // words per wave; 256 blocks * 4 waves * 16 = 16384
#define ROWS 34          // rows 0..31 written; 32,33 garbage, feed masked t=30,31
#define RST  72          // row stride in bf16 (36 dwords; 144B, 16B-aligned)
#define BUFE (ROWS * RST)

// Pack conv_w [F=128][E=64][K=3] fp32 -> B-fragment-ordered bf16 in ws:
// pw[((nt*12 + kk*4 + ks)*64 + lane)*8 + j]
//   = w[f=nt*32+(lane&31)][e=ks*16+(lane>>5)*8+j][kk]
__global__ __launch_bounds__(256)
void prep_pack_w(const float* __restrict__ w, __bf16* __restrict__ pw) {
  int i = blockIdx.x * 256 + threadIdx.x;   // 0..24575
  int j    = i & 7;
  int lane = (i >> 3) & 63;
  int ks   = (i >> 9) & 3;
  int t    = i >> 11;        // nt*3 + kk
  int kk   = t % 3;
  int nt   = t / 3;
  int f = nt * 32 + (lane & 31);
  int e = ks * 16 + (lane >> 5) * 8 + j;
  // destination index uses q = kk*4+ks within nt: ((nt*12 + kk*4 + ks)...)
  pw[(((nt * 12 + kk * 4 + ks) * 64 + lane) * 8) + j] = (__bf16)w[f * 192 + e * 3 + kk];
}

__global__ __launch_bounds__(256, 1)
void charcnn_mfma(const int* __restrict__ cid, const float* __restrict__ emb,
                  const float* __restrict__ bias, const __bf16* __restrict__ pw,
                  float* __restrict__ out) {
  // wave-private double buffers: 4 waves x 2 x 34*72 bf16 = 39168 B
  __shared__ __align__(16) __bf16 xT[4][2][BUFE];

  const int tid  = threadIdx.x;
  const int lane = tid & 63;
  const int wv   = tid >> 6;
  const int m    = lane & 31;    // t-row / char index / f-within-tile
  const int h    = lane >> 5;    // 0..1

  // persistent B fragments: all 128 f for this wave. 48 x 4 VGPR = 192.
  bf16x8 bfrag[48];
  const bf16x8* pwv = (const bf16x8*)pw;
#pragma unroll
  for (int q = 0; q < 48; ++q) bfrag[q] = pwv[q * 64 + lane];

  float vb[4];
#pragma unroll
  for (int nt = 0; nt < 4; ++nt) vb[nt] = bias[nt * 32 + m];

  const int gw = blockIdx.x * 4 + wv;    // 0..1023
  const int w0 = gw * NW;

  __bf16* const xw = &xT[wv][0][0];

  float4 pf[8];   // prefetched embedding rows for the next word

  // gather word w's embeddings into pf:
  // lane (m=char a, h=half): pf[s] = emb[ch[a]][16*(h+2s) .. +3? ] float4s
  auto gather = [&](int w) {
    int ch = cid[w * 32 + m];
    const float4* er = (const float4*)(emb + ch * 64);
#pragma unroll
    for (int s = 0; s < 4; ++s) {
      pf[s]     = er[h + 2 * s];        // dims c = 4*(h+2s) .. +3
      pf[s + 4] = er[h + 2 * s + 8];    // dims 32 + c
    }
  };

  // write pf into buffer b: dword[c*36 + a] = pack(emb[ch[a]][c], emb[ch[a]][32+c])
  auto put = [&](__bf16* b) {
    uint32_t* dst = (uint32_t*)b;
#pragma unroll
    for (int s = 0; s < 4; ++s) {
      float lv[4] = {pf[s].x, pf[s].y, pf[s].z, pf[s].w};
      float hv[4] = {pf[s + 4].x, pf[s + 4].y, pf[s + 4].z, pf[s + 4].w};
#pragma unroll
      for (int i = 0; i < 4; ++i) {
        uint32_t u = ((uint32_t)__builtin_bit_cast(uint16_t, (__bf16)hv[i]) << 16)
                   |  (uint32_t)__builtin_bit_cast(uint16_t, (__bf16)lv[i]);
        dst[(4 * (h + 2 * s) + i) * 36 + m] = u;   // row c = 4(h+2s)+i, col-pair a=m
      }
    }
  };

  f32x16 acc[4];

  auto mfma_word = [&](const __bf16* xb) {
#pragma unroll
    for (int nt = 0; nt < 4; ++nt)
#pragma unroll
      for (int r = 0; r < 16; ++r) acc[nt][r] = 0.0f;
#pragma unroll
    for (int kk = 0; kk < 3; ++kk) {
#pragma unroll
      for (int ks = 0; ks < 4; ++ks) {
        // A[m][k] = xT[m+kk][ks*16 + h*8 + j] -- one b128 read, reused 4x
        bf16x8 af = *(const bf16x8*)(xb + (m + kk) * RST + ks * 16 + h * 8);
#pragma unroll
        for (int nt = 0; nt < 4; ++nt)
          acc[nt] = __builtin_amdgcn_mfma_f32_32x32x16_bf16(
                      af, bfrag[nt * 12 + kk * 4 + ks], acc[nt], 0, 0, 0);
      }
    }
  };

  // max over t: t = (reg&3) + 8*(reg>>2) + 4*h; regs 14,15 on h=1 are t=30,31.
  auto epilogue = [&](int w) {
#pragma unroll
    for (int nt = 0; nt < 4; ++nt) {
      float m0 = acc[nt][0];
#pragma unroll
      for (int r = 1; r <= 13; ++r) m0 = fmaxf(m0, acc[nt][r]);
      float m1 = fmaxf(acc[nt][14], acc[nt][15]);
      float mm = (lane < 32) ? fmaxf(m0, m1) : m0;
      float ot = __shfl_xor(mm, 32, 64);
      float res = fmaxf(mm, ot) + vb[nt];
      if (lane < 32) out[w * 128 + nt * 32 + m] = res;
    }
  };

  gather(w0);
  put(xw);                       // word 0 -> buffer 0
#pragma unroll 1
  for (int i = 0; i < NW - 1; ++i) {
    const __bf16* bc = xw + (i & 1) * BUFE;
    __bf16*       bn = xw + ((i + 1) & 1) * BUFE;
    gather(w0 + i + 1);          // global loads in flight during MFMAs
    mfma_word(bc);
    put(bn);                     // stage next word (drains during epilogue)
    epilogue(w0 + i);
  }
  mfma_word(xw + ((NW - 1) & 1) * BUFE);
  epilogue(w0 + NW - 1);
}

extern "C" void kernel_launch(void* const* d_in, const int* in_sizes, int n_in,
                              void* d_out, int out_size, void* d_ws, size_t ws_size,
                              hipStream_t stream) {
  const int*   cid = (const int*)d_in[0];    // [32*512*32] int32
  const float* emb = (const float*)d_in[1];  // [101*64]  f32
  const float* cw  = (const float*)d_in[2];  // [128*64*3] f32
  const float* cb  = (const float*)d_in[3];  // [128] f32
  float* outp = (float*)d_out;               // [16384*128] f32
  __bf16* pw = (__bf16*)d_ws;                // 24576 bf16 = 48 KB

  hipLaunchKernelGGL(prep_pack_w, dim3(96), dim3(256), 0, stream, cw, pw);
  hipLaunchKernelGGL(charcnn_mfma, dim3(256), dim3(256), 0, stream,
                     cid, emb, cb, (const __bf16*)pw, outp);
}